// Round 12
// baseline (178.644 us; speedup 1.0000x reference)
//
#include <hip/hip_runtime.h>

typedef unsigned short u16;
typedef __attribute__((ext_vector_type(8))) short bf16x8;
typedef __attribute__((ext_vector_type(4))) float f32x4;

#define MFMA16(a, b, c) __builtin_amdgcn_mfma_f32_16x16x32_bf16(a, b, c, 0, 0, 0)

__device__ inline u16 f2bf(float f) {
    unsigned u = __float_as_uint(f);
    u = u + 0x7FFFu + ((u >> 16) & 1u);
    return (u16)(u >> 16);
}

__device__ inline float fast_exp2(float x) {
#if __has_builtin(__builtin_amdgcn_exp2f)
    return __builtin_amdgcn_exp2f(x);
#else
    return exp2f(x);
#endif
}

__device__ inline unsigned cvtpk(float lo, float hi) {
    unsigned r;
    asm("v_cvt_pk_bf16_f32 %0, %1, %2" : "=v"(r) : "v"(lo), "v"(hi));
    return r;
}

// j-permutation within each 64-block: jloc = 16t + 4lg + r  ->  32(t&1) + 8lg + 4(t>>1) + r
__device__ inline int vperm(int j) {
    return ((j >> 4) & 1) * 32 + ((j >> 2) & 3) * 8 + ((j >> 5) & 1) * 4 + (j & 3);
}

// ---------------- weight conversion
__global__ __launch_bounds__(256) void k_wconv(const float* qw, const float* pw, u16* qwb, u16* pwb) {
    int tid = blockIdx.x * 256 + threadIdx.x;
    int base = tid * 8;
    const float* src;
    u16* dst;
    if (base < 98304) { src = qw + base; dst = qwb + base; }
    else { src = pw + (base - 98304); dst = pwb + (base - 98304); }
    float4 v0 = *(const float4*)(src);
    float4 v1 = *(const float4*)(src + 4);
    ushort4 o0, o1;
    o0.x = f2bf(v0.x); o0.y = f2bf(v0.y); o0.z = f2bf(v0.z); o0.w = f2bf(v0.w);
    o1.x = f2bf(v1.x); o1.y = f2bf(v1.y); o1.z = f2bf(v1.z); o1.w = f2bf(v1.w);
    *(ushort4*)(dst) = o0;
    *(ushort4*)(dst + 4) = o1;
}

// ---------------- groupnorm stats stage 1
__global__ __launch_bounds__(256) void k_stats1(const float* x, float* psum, float* psumsq) {
    int bid = blockIdx.x;
    int gi = bid >> 4, s = bid & 15;
    const float* base = x + (size_t)gi * 131072 + s * 8192;
    int t = threadIdx.x;
    float s1 = 0.f, s2 = 0.f;
#pragma unroll
    for (int it = 0; it < 8; it++) {
        float4 v = *(const float4*)(base + it * 1024 + t * 4);
        s1 += (v.x + v.y) + (v.z + v.w);
        s2 += (v.x * v.x + v.y * v.y) + (v.z * v.z + v.w * v.w);
    }
    for (int msk = 1; msk < 64; msk <<= 1) {
        s1 += __shfl_xor(s1, msk);
        s2 += __shfl_xor(s2, msk);
    }
    __shared__ float r1[4], r2[4];
    int w = t >> 6;
    if ((t & 63) == 0) { r1[w] = s1; r2[w] = s2; }
    __syncthreads();
    if (t == 0) {
        psum[bid] = (r1[0] + r1[1]) + (r1[2] + r1[3]);
        psumsq[bid] = (r2[0] + r2[1]) + (r2[2] + r2[3]);
    }
}

// ---------------- groupnorm stats stage 2
__global__ void k_stats2(const float* psum, const float* psumsq, float* meanb, float* rstdb) {
    int t = threadIdx.x;
    if (t < 16) {
        float s1 = 0.f, s2 = 0.f;
        for (int i = 0; i < 16; i++) { s1 += psum[t * 16 + i]; s2 += psumsq[t * 16 + i]; }
        float mu = s1 * (1.0f / 131072.0f);
        float var = s2 * (1.0f / 131072.0f) - mu * mu;
        meanb[t] = mu;
        rstdb[t] = rsqrtf(var + 1e-5f);
    }
}

// ---------------- normalize + transpose
__global__ __launch_bounds__(256) void k_normt(const float* x, const float* gw, const float* gb,
                                               const float* meanb, const float* rstdb, u16* xnt) {
    int bid = blockIdx.x;
    int b = bid >> 10, ct = (bid >> 7) & 7, nt = bid & 127;
    int t = threadIdx.x;
    int r = t >> 3, q = t & 7;
    __shared__ float tile[32][33];
    int gi = b * 8 + ct;
    float mu = meanb[gi], rs = rstdb[gi];
    int c = ct * 32 + r;
    float wv = gw[c] * rs;
    float bv = gb[c] - mu * wv;
    float4 v = *(const float4*)(x + ((size_t)(b * 256 + c)) * 4096 + nt * 32 + q * 4);
    tile[r][q * 4 + 0] = v.x * wv + bv;
    tile[r][q * 4 + 1] = v.y * wv + bv;
    tile[r][q * 4 + 2] = v.z * wv + bv;
    tile[r][q * 4 + 3] = v.w * wv + bv;
    __syncthreads();
    int cq = q * 4;
    ushort4 o;
    o.x = f2bf(tile[cq + 0][r]);
    o.y = f2bf(tile[cq + 1][r]);
    o.z = f2bf(tile[cq + 2][r]);
    o.w = f2bf(tile[cq + 3][r]);
    *(ushort4*)(xnt + ((size_t)(b * 4096 + nt * 32 + r)) * 256 + ct * 32 + cq) = o;
}

// ---------------- QKV GEMM. grid 384 = b(2) x mt(3) x nt(64). Tile 128o x 64n, wave 64x32.
// Q pre-scaled; V columns bit-permuted per 64-block.
__global__ __launch_bounds__(256) void k_qkv(const u16* __restrict__ wq, const u16* __restrict__ xnt,
                                             u16* __restrict__ qkvt, u16* __restrict__ vnat) {
    int bid = blockIdx.x;
    int b = bid / 192;
    int r2 = bid % 192;
    int mt = r2 >> 6, nt = r2 & 63;
    int tid = threadIdx.x;
    int w = tid >> 6, lane = tid & 63, lr = lane & 15, lg = lane >> 4;
    int wr = w >> 1, wc = w & 1;
    int ob = mt * 128 + wr * 64;
    int nb = nt * 64 + wc * 32;
    f32x4 acc[4][2];
#pragma unroll
    for (int mi = 0; mi < 4; mi++)
#pragma unroll
        for (int ni = 0; ni < 2; ni++) acc[mi][ni] = (f32x4){0.f, 0.f, 0.f, 0.f};
    const u16* apan = wq + (ob + lr) * 256 + lg * 8;
    const u16* bpan = xnt + ((size_t)(b * 4096 + nb + lr)) * 256 + lg * 8;
#pragma unroll
    for (int kk = 0; kk < 256; kk += 32) {
        bf16x8 af[4], bfv[2];
#pragma unroll
        for (int mi = 0; mi < 4; mi++) af[mi] = *(const bf16x8*)(apan + mi * 16 * 256 + kk);
#pragma unroll
        for (int ni = 0; ni < 2; ni++) bfv[ni] = *(const bf16x8*)(bpan + ni * 16 * 256 + kk);
#pragma unroll
        for (int mi = 0; mi < 4; mi++)
#pragma unroll
            for (int ni = 0; ni < 2; ni++) acc[mi][ni] = MFMA16(af[mi], bfv[ni], acc[mi][ni]);
    }
    if (mt == 0) {
        const float sl = 0.25503485f;  // (1/sqrt(32)) * log2(e) folded into Q
#pragma unroll
        for (int mi = 0; mi < 4; mi++)
#pragma unroll
            for (int ni = 0; ni < 2; ni++)
#pragma unroll
                for (int r = 0; r < 4; r++) acc[mi][ni][r] *= sl;
    }
    if (mt < 2) {
#pragma unroll
        for (int mi = 0; mi < 4; mi++)
#pragma unroll
            for (int ni = 0; ni < 2; ni++) {
                int o0 = ob + mi * 16 + lg * 4;
                int n = nb + ni * 16 + lr;
                ushort4 pk;
                pk.x = f2bf(acc[mi][ni][0]);
                pk.y = f2bf(acc[mi][ni][1]);
                pk.z = f2bf(acc[mi][ni][2]);
                pk.w = f2bf(acc[mi][ni][3]);
                *(ushort4*)(qkvt + ((size_t)(b * 4096 + n)) * 256 + o0) = pk;
            }
    } else {
#pragma unroll
        for (int mi = 0; mi < 4; mi++)
#pragma unroll
            for (int ni = 0; ni < 2; ni++) {
                int n = nb + ni * 16 + lr;
                int np = (n & ~63) | vperm(n & 63);
#pragma unroll
                for (int r = 0; r < 4; r++) {
                    int o = ob + mi * 16 + lg * 4 + r - 256;
                    vnat[((size_t)(b * 128 + o)) * 4096 + np] = f2bf(acc[mi][ni][r]);
                }
            }
    }
}

// ---------------- flash attention, j-split, 2 i-tiles/wave (round-8 softmax, regrid only).
// grid 1024: ibk=bid&31, h=(bid>>5)&3, b=(bid>>7)&1, s=bid>>8. Block: 1024 j's, 128 i's.
__global__ __launch_bounds__(256) void k_attn(const u16* __restrict__ qkvt, const u16* __restrict__ vnat,
                                              float* __restrict__ po, float* __restrict__ pml) {
    int bid = blockIdx.x;
    int ibk = bid & 31;
    int h = (bid >> 5) & 3;
    int b = (bid >> 7) & 1;
    int s = bid >> 8;
    int tid = threadIdx.x;
    int w = tid >> 6, lane = tid & 63, lr = lane & 15, lg = lane >> 4;
    int i0 = ibk * 128 + w * 32;

    bf16x8 qf[2];
#pragma unroll
    for (int ti = 0; ti < 2; ti++)
        qf[ti] = *(const bf16x8*)(qkvt + ((size_t)(b * 4096 + i0 + ti * 16 + lr)) * 256 + h * 32 + lg * 8);

    f32x4 oa0[2], oa1[2];
    float m_[2], l_[2];
#pragma unroll
    for (int ti = 0; ti < 2; ti++) {
        oa0[ti] = (f32x4){0.f, 0.f, 0.f, 0.f};
        oa1[ti] = (f32x4){0.f, 0.f, 0.f, 0.f};
        m_[ti] = -1e30f;
        l_[ti] = 0.f;
    }

    const u16* kbase = qkvt + (size_t)b * 4096 * 256 + (size_t)lr * 256 + 128 + h * 32 + lg * 8;
    const u16* vbase = vnat + ((size_t)((b * 4 + h) * 32 + lr)) * 4096 + lg * 8;

    int jb0 = s * 1024;
    for (int jb = jb0; jb < jb0 + 1024; jb += 64) {
        const u16* kp = kbase + (size_t)jb * 256;
        bf16x8 kf0 = *(const bf16x8*)(kp);
        bf16x8 kf1 = *(const bf16x8*)(kp + 16 * 256);
        bf16x8 kf2 = *(const bf16x8*)(kp + 32 * 256);
        bf16x8 kf3 = *(const bf16x8*)(kp + 48 * 256);
        const u16* vp = vbase + jb;
        bf16x8 va00 = *(const bf16x8*)(vp);
        bf16x8 va01 = *(const bf16x8*)(vp + 32);
        bf16x8 va10 = *(const bf16x8*)(vp + 16 * 4096);
        bf16x8 va11 = *(const bf16x8*)(vp + 16 * 4096 + 32);

#pragma unroll
        for (int ti = 0; ti < 2; ti++) {
            f32x4 z = {0.f, 0.f, 0.f, 0.f};
            f32x4 s0 = MFMA16(kf0, qf[ti], z);   // lane: i = lr, j_loc = 16t + 4lg + r
            f32x4 s1 = MFMA16(kf1, qf[ti], z);
            f32x4 s2 = MFMA16(kf2, qf[ti], z);
            f32x4 s3 = MFMA16(kf3, qf[ti], z);

            float tm = fmaxf(
                fmaxf(fmaxf(fmaxf(s0[0], s0[1]), fmaxf(s0[2], s0[3])),
                      fmaxf(fmaxf(s1[0], s1[1]), fmaxf(s1[2], s1[3]))),
                fmaxf(fmaxf(fmaxf(s2[0], s2[1]), fmaxf(s2[2], s2[3])),
                      fmaxf(fmaxf(s3[0], s3[1]), fmaxf(s3[2], s3[3]))));
            tm = fmaxf(tm, __shfl_xor(tm, 16));
            tm = fmaxf(tm, __shfl_xor(tm, 32));

            if (__any(tm > m_[ti])) {
                float mn = fmaxf(m_[ti], tm);
                float corr = fast_exp2(m_[ti] - mn);
                m_[ti] = mn;
                l_[ti] *= corr;
                oa0[ti][0] *= corr; oa0[ti][1] *= corr; oa0[ti][2] *= corr; oa0[ti][3] *= corr;
                oa1[ti][0] *= corr; oa1[ti][1] *= corr; oa1[ti][2] *= corr; oa1[ti][3] *= corr;
            }
            float mc = m_[ti];

            float p00 = fast_exp2(s0[0] - mc), p01 = fast_exp2(s0[1] - mc);
            float p02 = fast_exp2(s0[2] - mc), p03 = fast_exp2(s0[3] - mc);
            float p10 = fast_exp2(s1[0] - mc), p11 = fast_exp2(s1[1] - mc);
            float p12 = fast_exp2(s1[2] - mc), p13 = fast_exp2(s1[3] - mc);
            float p20 = fast_exp2(s2[0] - mc), p21 = fast_exp2(s2[1] - mc);
            float p22 = fast_exp2(s2[2] - mc), p23 = fast_exp2(s2[3] - mc);
            float p30 = fast_exp2(s3[0] - mc), p31 = fast_exp2(s3[1] - mc);
            float p32 = fast_exp2(s3[2] - mc), p33 = fast_exp2(s3[3] - mc);

            float rs = (((p00 + p01) + (p02 + p03)) + ((p10 + p11) + (p12 + p13)))
                     + (((p20 + p21) + (p22 + p23)) + ((p30 + p31) + (p32 + p33)));
            rs += __shfl_xor(rs, 16);
            rs += __shfl_xor(rs, 32);
            l_[ti] += rs;

            union { bf16x8 v; unsigned u[4]; } pb0, pb1;
            pb0.u[0] = cvtpk(p00, p01); pb0.u[1] = cvtpk(p02, p03);
            pb0.u[2] = cvtpk(p20, p21); pb0.u[3] = cvtpk(p22, p23);
            pb1.u[0] = cvtpk(p10, p11); pb1.u[1] = cvtpk(p12, p13);
            pb1.u[2] = cvtpk(p30, p31); pb1.u[3] = cvtpk(p32, p33);

            oa0[ti] = MFMA16(va00, pb0.v, oa0[ti]);
            oa0[ti] = MFMA16(va01, pb1.v, oa0[ti]);
            oa1[ti] = MFMA16(va10, pb0.v, oa1[ti]);
            oa1[ti] = MFMA16(va11, pb1.v, oa1[ti]);
        }
    }

#pragma unroll
    for (int ti = 0; ti < 2; ti++) {
        size_t row = (size_t)(b * 4 + h) * 4096 + i0 + ti * 16 + lr;
        float* prow = po + (row * 4 + s) * 32;
        *(f32x4*)(prow + 4 * lg) = oa0[ti];
        *(f32x4*)(prow + 16 + 4 * lg) = oa1[ti];
        if (lg == 0) {
            pml[(row * 4 + s) * 2 + 0] = m_[ti];
            pml[(row * 4 + s) * 2 + 1] = l_[ti];
        }
    }
}

// ---------------- combine split partials -> attnt bf16
__global__ __launch_bounds__(256) void k_comb(const float* __restrict__ po, const float* __restrict__ pml,
                                              u16* __restrict__ attnt) {
    int idx = blockIdx.x * 256 + threadIdx.x;
    int d0 = (idx & 7) * 4;
    int row = idx >> 3;
    float m0 = pml[(row * 4 + 0) * 2], l0 = pml[(row * 4 + 0) * 2 + 1];
    float m1 = pml[(row * 4 + 1) * 2], l1 = pml[(row * 4 + 1) * 2 + 1];
    float m2 = pml[(row * 4 + 2) * 2], l2 = pml[(row * 4 + 2) * 2 + 1];
    float m3 = pml[(row * 4 + 3) * 2], l3 = pml[(row * 4 + 3) * 2 + 1];
    float M = fmaxf(fmaxf(m0, m1), fmaxf(m2, m3));
    float w0 = fast_exp2(m0 - M), w1 = fast_exp2(m1 - M);
    float w2 = fast_exp2(m2 - M), w3 = fast_exp2(m3 - M);
    float inv = 1.0f / (w0 * l0 + w1 * l1 + w2 * l2 + w3 * l3);
    f32x4 a0 = *(const f32x4*)(po + ((size_t)row * 4 + 0) * 32 + d0);
    f32x4 a1 = *(const f32x4*)(po + ((size_t)row * 4 + 1) * 32 + d0);
    f32x4 a2 = *(const f32x4*)(po + ((size_t)row * 4 + 2) * 32 + d0);
    f32x4 a3 = *(const f32x4*)(po + ((size_t)row * 4 + 3) * 32 + d0);
    ushort4 st;
    st.x = f2bf((w0 * a0[0] + w1 * a1[0] + w2 * a2[0] + w3 * a3[0]) * inv);
    st.y = f2bf((w0 * a0[1] + w1 * a1[1] + w2 * a2[1] + w3 * a3[1]) * inv);
    st.z = f2bf((w0 * a0[2] + w1 * a1[2] + w2 * a2[2] + w3 * a3[2]) * inv);
    st.w = f2bf((w0 * a0[3] + w1 * a1[3] + w2 * a2[3] + w3 * a3[3]) * inv);
    int i = row & 4095;
    int bh = row >> 12;
    int b = bh >> 2, h = bh & 3;
    *(ushort4*)(attnt + ((size_t)(b * 4096 + i)) * 128 + h * 32 + d0) = st;
}

// ---------------- proj GEMM + bias + residual. grid 256 = b(2) x mt(4) x nt(32).
// Tile 64c x 128n, wave 32x64.
__global__ __launch_bounds__(256) void k_proj(const u16* __restrict__ wp, const u16* __restrict__ attnt,
                                              const float* __restrict__ pb, const float* __restrict__ x,
                                              float* __restrict__ out) {
    int bid = blockIdx.x;
    int b = bid >> 7;
    int r2 = bid & 127;
    int mt = r2 >> 5, nt = r2 & 31;
    int tid = threadIdx.x;
    int w = tid >> 6, lane = tid & 63, lr = lane & 15, lg = lane >> 4;
    int wr = w >> 1, wc = w & 1;
    int cb = mt * 64 + wr * 32;
    int nb = nt * 128 + wc * 64;
    f32x4 acc[2][4];
#pragma unroll
    for (int mi = 0; mi < 2; mi++)
#pragma unroll
        for (int ni = 0; ni < 4; ni++) acc[mi][ni] = (f32x4){0.f, 0.f, 0.f, 0.f};
    const u16* apan = wp + (cb + lr) * 128 + lg * 8;
    const u16* bpan = attnt + ((size_t)(b * 4096 + nb + lr)) * 128 + lg * 8;
#pragma unroll
    for (int kk = 0; kk < 128; kk += 32) {
        bf16x8 af[2], bfv[4];
#pragma unroll
        for (int mi = 0; mi < 2; mi++) af[mi] = *(const bf16x8*)(apan + mi * 16 * 128 + kk);
#pragma unroll
        for (int ni = 0; ni < 4; ni++) bfv[ni] = *(const bf16x8*)(bpan + ni * 16 * 128 + kk);
#pragma unroll
        for (int mi = 0; mi < 2; mi++)
#pragma unroll
            for (int ni = 0; ni < 4; ni++) acc[mi][ni] = MFMA16(af[mi], bfv[ni], acc[mi][ni]);
    }
#pragma unroll
    for (int mi = 0; mi < 2; mi++)
#pragma unroll
        for (int ni = 0; ni < 4; ni++) {
            int n = nb + ni * 16 + lr;
#pragma unroll
            for (int r = 0; r < 4; r++) {
                int c = cb + mi * 16 + lg * 4 + r;
                size_t idx = ((size_t)(b * 256 + c)) * 4096 + n;
                out[idx] = acc[mi][ni][r] + pb[c] + x[idx];
            }
        }
}

extern "C" void kernel_launch(void* const* d_in, const int* in_sizes, int n_in,
                              void* d_out, int out_size, void* d_ws, size_t ws_size,
                              hipStream_t stream) {
    const float* x = (const float*)d_in[0];
    const float* nw = (const float*)d_in[1];
    const float* nbv = (const float*)d_in[2];
    const float* qw = (const float*)d_in[3];
    const float* pw = (const float*)d_in[4];
    const float* pb = (const float*)d_in[5];
    float* out = (float*)d_out;
    char* ws = (char*)d_ws;

    float* psum = (float*)(ws + 0);
    float* psumsq = (float*)(ws + 1024);
    float* meanb = (float*)(ws + 2048);
    float* rstdb = (float*)(ws + 2112);
    u16* qwb = (u16*)(ws + 4096);            // ends 200704
    u16* pwb = (u16*)(ws + 200704);          // ends 266240
    u16* xnt = (u16*)(ws + 266240);          // ends 4460544
    u16* qkvt = (u16*)(ws + 4460544);        // ends 8654848
    u16* vnat = (u16*)(ws + 8654848);        // ends 10752000
    u16* attnt = (u16*)(ws + 10752000);      // ends 12849152
    float* po = (float*)(ws + 12849152);     // 16 MB, ends 29626368
    float* pml = (float*)(ws + 29626368);    // 1 MB, ends 30674944

    k_wconv<<<64, 256, 0, stream>>>(qw, pw, qwb, pwb);
    k_stats1<<<256, 256, 0, stream>>>(x, psum, psumsq);
    k_stats2<<<1, 64, 0, stream>>>(psum, psumsq, meanb, rstdb);
    k_normt<<<2048, 256, 0, stream>>>(x, nw, nbv, meanb, rstdb, xnt);
    k_qkv<<<384, 256, 0, stream>>>(qwb, xnt, qkvt, vnat);
    k_attn<<<1024, 256, 0, stream>>>(qkvt, vnat, po, pml);
    k_comb<<<1024, 256, 0, stream>>>(po, pml, attnt);
    k_proj<<<256, 256, 0, stream>>>(pwb, attnt, pb, x, out);
}

// Round 13
// 153.057 us; speedup vs baseline: 1.1672x; 1.1672x over previous
//
#include <hip/hip_runtime.h>

typedef unsigned short u16;
typedef __attribute__((ext_vector_type(8))) short bf16x8;
typedef __attribute__((ext_vector_type(4))) float f32x4;

#define MFMA16(a, b, c) __builtin_amdgcn_mfma_f32_16x16x32_bf16(a, b, c, 0, 0, 0)

__device__ inline u16 f2bf(float f) {
    unsigned u = __float_as_uint(f);
    u = u + 0x7FFFu + ((u >> 16) & 1u);
    return (u16)(u >> 16);
}

__device__ inline float fast_exp2(float x) {
#if __has_builtin(__builtin_amdgcn_exp2f)
    return __builtin_amdgcn_exp2f(x);
#else
    return exp2f(x);
#endif
}

__device__ inline unsigned cvtpk(float lo, float hi) {
    unsigned r;
    asm("v_cvt_pk_bf16_f32 %0, %1, %2" : "=v"(r) : "v"(lo), "v"(hi));
    return r;
}

// j-permutation within each 64-block: jloc = 16t + 4lg + r  ->  32(t&1) + 8lg + 4(t>>1) + r
__device__ inline int vperm(int j) {
    return ((j >> 4) & 1) * 32 + ((j >> 2) & 3) * 8 + ((j >> 5) & 1) * 4 + (j & 3);
}

// ---------------- weight conversion
__global__ __launch_bounds__(256) void k_wconv(const float* qw, const float* pw, u16* qwb, u16* pwb) {
    int tid = blockIdx.x * 256 + threadIdx.x;
    int base = tid * 8;
    const float* src;
    u16* dst;
    if (base < 98304) { src = qw + base; dst = qwb + base; }
    else { src = pw + (base - 98304); dst = pwb + (base - 98304); }
    float4 v0 = *(const float4*)(src);
    float4 v1 = *(const float4*)(src + 4);
    ushort4 o0, o1;
    o0.x = f2bf(v0.x); o0.y = f2bf(v0.y); o0.z = f2bf(v0.z); o0.w = f2bf(v0.w);
    o1.x = f2bf(v1.x); o1.y = f2bf(v1.y); o1.z = f2bf(v1.z); o1.w = f2bf(v1.w);
    *(ushort4*)(dst) = o0;
    *(ushort4*)(dst + 4) = o1;
}

// ---------------- groupnorm stats stage 1
__global__ __launch_bounds__(256) void k_stats1(const float* x, float* psum, float* psumsq) {
    int bid = blockIdx.x;
    int gi = bid >> 4, s = bid & 15;
    const float* base = x + (size_t)gi * 131072 + s * 8192;
    int t = threadIdx.x;
    float s1 = 0.f, s2 = 0.f;
#pragma unroll
    for (int it = 0; it < 8; it++) {
        float4 v = *(const float4*)(base + it * 1024 + t * 4);
        s1 += (v.x + v.y) + (v.z + v.w);
        s2 += (v.x * v.x + v.y * v.y) + (v.z * v.z + v.w * v.w);
    }
    for (int msk = 1; msk < 64; msk <<= 1) {
        s1 += __shfl_xor(s1, msk);
        s2 += __shfl_xor(s2, msk);
    }
    __shared__ float r1[4], r2[4];
    int w = t >> 6;
    if ((t & 63) == 0) { r1[w] = s1; r2[w] = s2; }
    __syncthreads();
    if (t == 0) {
        psum[bid] = (r1[0] + r1[1]) + (r1[2] + r1[3]);
        psumsq[bid] = (r2[0] + r2[1]) + (r2[2] + r2[3]);
    }
}

// ---------------- groupnorm stats stage 2
__global__ void k_stats2(const float* psum, const float* psumsq, float* meanb, float* rstdb) {
    int t = threadIdx.x;
    if (t < 16) {
        float s1 = 0.f, s2 = 0.f;
        for (int i = 0; i < 16; i++) { s1 += psum[t * 16 + i]; s2 += psumsq[t * 16 + i]; }
        float mu = s1 * (1.0f / 131072.0f);
        float var = s2 * (1.0f / 131072.0f) - mu * mu;
        meanb[t] = mu;
        rstdb[t] = rsqrtf(var + 1e-5f);
    }
}

// ---------------- normalize + transpose
__global__ __launch_bounds__(256) void k_normt(const float* x, const float* gw, const float* gb,
                                               const float* meanb, const float* rstdb, u16* xnt) {
    int bid = blockIdx.x;
    int b = bid >> 10, ct = (bid >> 7) & 7, nt = bid & 127;
    int t = threadIdx.x;
    int r = t >> 3, q = t & 7;
    __shared__ float tile[32][33];
    int gi = b * 8 + ct;
    float mu = meanb[gi], rs = rstdb[gi];
    int c = ct * 32 + r;
    float wv = gw[c] * rs;
    float bv = gb[c] - mu * wv;
    float4 v = *(const float4*)(x + ((size_t)(b * 256 + c)) * 4096 + nt * 32 + q * 4);
    tile[r][q * 4 + 0] = v.x * wv + bv;
    tile[r][q * 4 + 1] = v.y * wv + bv;
    tile[r][q * 4 + 2] = v.z * wv + bv;
    tile[r][q * 4 + 3] = v.w * wv + bv;
    __syncthreads();
    int cq = q * 4;
    ushort4 o;
    o.x = f2bf(tile[cq + 0][r]);
    o.y = f2bf(tile[cq + 1][r]);
    o.z = f2bf(tile[cq + 2][r]);
    o.w = f2bf(tile[cq + 3][r]);
    *(ushort4*)(xnt + ((size_t)(b * 4096 + nt * 32 + r)) * 256 + ct * 32 + cq) = o;
}

// ---------------- QKV GEMM. grid 384 = b(2) x mt(3) x nt(64). Tile 128o x 64n, wave 64x32.
// Q pre-scaled; V columns bit-permuted per 64-block.
__global__ __launch_bounds__(256) void k_qkv(const u16* __restrict__ wq, const u16* __restrict__ xnt,
                                             u16* __restrict__ qkvt, u16* __restrict__ vnat) {
    int bid = blockIdx.x;
    int b = bid / 192;
    int r2 = bid % 192;
    int mt = r2 >> 6, nt = r2 & 63;
    int tid = threadIdx.x;
    int w = tid >> 6, lane = tid & 63, lr = lane & 15, lg = lane >> 4;
    int wr = w >> 1, wc = w & 1;
    int ob = mt * 128 + wr * 64;
    int nb = nt * 64 + wc * 32;
    f32x4 acc[4][2];
#pragma unroll
    for (int mi = 0; mi < 4; mi++)
#pragma unroll
        for (int ni = 0; ni < 2; ni++) acc[mi][ni] = (f32x4){0.f, 0.f, 0.f, 0.f};
    const u16* apan = wq + (ob + lr) * 256 + lg * 8;
    const u16* bpan = xnt + ((size_t)(b * 4096 + nb + lr)) * 256 + lg * 8;
#pragma unroll
    for (int kk = 0; kk < 256; kk += 32) {
        bf16x8 af[4], bfv[2];
#pragma unroll
        for (int mi = 0; mi < 4; mi++) af[mi] = *(const bf16x8*)(apan + mi * 16 * 256 + kk);
#pragma unroll
        for (int ni = 0; ni < 2; ni++) bfv[ni] = *(const bf16x8*)(bpan + ni * 16 * 256 + kk);
#pragma unroll
        for (int mi = 0; mi < 4; mi++)
#pragma unroll
            for (int ni = 0; ni < 2; ni++) acc[mi][ni] = MFMA16(af[mi], bfv[ni], acc[mi][ni]);
    }
    if (mt == 0) {
        const float sl = 0.25503485f;  // (1/sqrt(32)) * log2(e) folded into Q
#pragma unroll
        for (int mi = 0; mi < 4; mi++)
#pragma unroll
            for (int ni = 0; ni < 2; ni++)
#pragma unroll
                for (int r = 0; r < 4; r++) acc[mi][ni][r] *= sl;
    }
    if (mt < 2) {
#pragma unroll
        for (int mi = 0; mi < 4; mi++)
#pragma unroll
            for (int ni = 0; ni < 2; ni++) {
                int o0 = ob + mi * 16 + lg * 4;
                int n = nb + ni * 16 + lr;
                ushort4 pk;
                pk.x = f2bf(acc[mi][ni][0]);
                pk.y = f2bf(acc[mi][ni][1]);
                pk.z = f2bf(acc[mi][ni][2]);
                pk.w = f2bf(acc[mi][ni][3]);
                *(ushort4*)(qkvt + ((size_t)(b * 4096 + n)) * 256 + o0) = pk;
            }
    } else {
#pragma unroll
        for (int mi = 0; mi < 4; mi++)
#pragma unroll
            for (int ni = 0; ni < 2; ni++) {
                int n = nb + ni * 16 + lr;
                int np = (n & ~63) | vperm(n & 63);
#pragma unroll
                for (int r = 0; r < 4; r++) {
                    int o = ob + mi * 16 + lg * 4 + r - 256;
                    vnat[((size_t)(b * 128 + o)) * 4096 + np] = f2bf(acc[mi][ni][r]);
                }
            }
    }
}

// ---------------- flash attention, j-split, 4 i-tiles per wave (4x K/V reuse) — round-8 verified.
// grid 512: ibk=bid&15, h=(bid>>4)&3, b=(bid>>6)&1, s=bid>>7. Each block: 1024 j's, 256 i's.
__global__ __launch_bounds__(256) void k_attn(const u16* __restrict__ qkvt, const u16* __restrict__ vnat,
                                              float* __restrict__ po, float* __restrict__ pml) {
    int bid = blockIdx.x;
    int ibk = bid & 15;
    int h = (bid >> 4) & 3;
    int b = (bid >> 6) & 1;
    int s = bid >> 7;
    int tid = threadIdx.x;
    int w = tid >> 6, lane = tid & 63, lr = lane & 15, lg = lane >> 4;
    int i0 = ibk * 256 + w * 64;

    bf16x8 qf[4];
#pragma unroll
    for (int ti = 0; ti < 4; ti++)
        qf[ti] = *(const bf16x8*)(qkvt + ((size_t)(b * 4096 + i0 + ti * 16 + lr)) * 256 + h * 32 + lg * 8);

    f32x4 oa0[4], oa1[4];
    float m_[4], l_[4];
#pragma unroll
    for (int ti = 0; ti < 4; ti++) {
        oa0[ti] = (f32x4){0.f, 0.f, 0.f, 0.f};
        oa1[ti] = (f32x4){0.f, 0.f, 0.f, 0.f};
        m_[ti] = -1e30f;
        l_[ti] = 0.f;
    }

    const u16* kbase = qkvt + (size_t)b * 4096 * 256 + (size_t)lr * 256 + 128 + h * 32 + lg * 8;
    const u16* vbase = vnat + ((size_t)((b * 4 + h) * 32 + lr)) * 4096 + lg * 8;

    int jb0 = s * 1024;
    for (int jb = jb0; jb < jb0 + 1024; jb += 64) {
        const u16* kp = kbase + (size_t)jb * 256;
        bf16x8 kf0 = *(const bf16x8*)(kp);
        bf16x8 kf1 = *(const bf16x8*)(kp + 16 * 256);
        bf16x8 kf2 = *(const bf16x8*)(kp + 32 * 256);
        bf16x8 kf3 = *(const bf16x8*)(kp + 48 * 256);
        const u16* vp = vbase + jb;
        bf16x8 va00 = *(const bf16x8*)(vp);
        bf16x8 va01 = *(const bf16x8*)(vp + 32);
        bf16x8 va10 = *(const bf16x8*)(vp + 16 * 4096);
        bf16x8 va11 = *(const bf16x8*)(vp + 16 * 4096 + 32);

#pragma unroll
        for (int ti = 0; ti < 4; ti++) {
            f32x4 z = {0.f, 0.f, 0.f, 0.f};
            f32x4 s0 = MFMA16(kf0, qf[ti], z);   // lane: i = lr, j_loc = 16t + 4lg + r
            f32x4 s1 = MFMA16(kf1, qf[ti], z);
            f32x4 s2 = MFMA16(kf2, qf[ti], z);
            f32x4 s3 = MFMA16(kf3, qf[ti], z);

            float tm = fmaxf(
                fmaxf(fmaxf(fmaxf(s0[0], s0[1]), fmaxf(s0[2], s0[3])),
                      fmaxf(fmaxf(s1[0], s1[1]), fmaxf(s1[2], s1[3]))),
                fmaxf(fmaxf(fmaxf(s2[0], s2[1]), fmaxf(s2[2], s2[3])),
                      fmaxf(fmaxf(s3[0], s3[1]), fmaxf(s3[2], s3[3]))));
            tm = fmaxf(tm, __shfl_xor(tm, 16));
            tm = fmaxf(tm, __shfl_xor(tm, 32));

            if (__any(tm > m_[ti])) {
                float mn = fmaxf(m_[ti], tm);
                float corr = fast_exp2(m_[ti] - mn);
                m_[ti] = mn;
                l_[ti] *= corr;
                oa0[ti][0] *= corr; oa0[ti][1] *= corr; oa0[ti][2] *= corr; oa0[ti][3] *= corr;
                oa1[ti][0] *= corr; oa1[ti][1] *= corr; oa1[ti][2] *= corr; oa1[ti][3] *= corr;
            }
            float mc = m_[ti];

            float p00 = fast_exp2(s0[0] - mc), p01 = fast_exp2(s0[1] - mc);
            float p02 = fast_exp2(s0[2] - mc), p03 = fast_exp2(s0[3] - mc);
            float p10 = fast_exp2(s1[0] - mc), p11 = fast_exp2(s1[1] - mc);
            float p12 = fast_exp2(s1[2] - mc), p13 = fast_exp2(s1[3] - mc);
            float p20 = fast_exp2(s2[0] - mc), p21 = fast_exp2(s2[1] - mc);
            float p22 = fast_exp2(s2[2] - mc), p23 = fast_exp2(s2[3] - mc);
            float p30 = fast_exp2(s3[0] - mc), p31 = fast_exp2(s3[1] - mc);
            float p32 = fast_exp2(s3[2] - mc), p33 = fast_exp2(s3[3] - mc);

            float rs = (((p00 + p01) + (p02 + p03)) + ((p10 + p11) + (p12 + p13)))
                     + (((p20 + p21) + (p22 + p23)) + ((p30 + p31) + (p32 + p33)));
            rs += __shfl_xor(rs, 16);
            rs += __shfl_xor(rs, 32);
            l_[ti] += rs;

            union { bf16x8 v; unsigned u[4]; } pb0, pb1;
            pb0.u[0] = cvtpk(p00, p01); pb0.u[1] = cvtpk(p02, p03);
            pb0.u[2] = cvtpk(p20, p21); pb0.u[3] = cvtpk(p22, p23);
            pb1.u[0] = cvtpk(p10, p11); pb1.u[1] = cvtpk(p12, p13);
            pb1.u[2] = cvtpk(p30, p31); pb1.u[3] = cvtpk(p32, p33);

            oa0[ti] = MFMA16(va00, pb0.v, oa0[ti]);
            oa0[ti] = MFMA16(va01, pb1.v, oa0[ti]);
            oa1[ti] = MFMA16(va10, pb0.v, oa1[ti]);
            oa1[ti] = MFMA16(va11, pb1.v, oa1[ti]);
        }
    }

#pragma unroll
    for (int ti = 0; ti < 4; ti++) {
        size_t row = (size_t)(b * 4 + h) * 4096 + i0 + ti * 16 + lr;
        float* prow = po + (row * 4 + s) * 32;
        *(f32x4*)(prow + 4 * lg) = oa0[ti];
        *(f32x4*)(prow + 16 + 4 * lg) = oa1[ti];
        if (lg == 0) {
            pml[(row * 4 + s) * 2 + 0] = m_[ti];
            pml[(row * 4 + s) * 2 + 1] = l_[ti];
        }
    }
}

// ---------------- combine split partials -> attnt bf16
// grid 1024 x 256: each thread one (row, d-quad). row = (b*4+h)*4096 + i.
__global__ __launch_bounds__(256) void k_comb(const float* __restrict__ po, const float* __restrict__ pml,
                                              u16* __restrict__ attnt) {
    int idx = blockIdx.x * 256 + threadIdx.x;
    int d0 = (idx & 7) * 4;
    int row = idx >> 3;
    float m0 = pml[(row * 4 + 0) * 2], l0 = pml[(row * 4 + 0) * 2 + 1];
    float m1 = pml[(row * 4 + 1) * 2], l1 = pml[(row * 4 + 1) * 2 + 1];
    float m2 = pml[(row * 4 + 2) * 2], l2 = pml[(row * 4 + 2) * 2 + 1];
    float m3 = pml[(row * 4 + 3) * 2], l3 = pml[(row * 4 + 3) * 2 + 1];
    float M = fmaxf(fmaxf(m0, m1), fmaxf(m2, m3));
    float w0 = fast_exp2(m0 - M), w1 = fast_exp2(m1 - M);
    float w2 = fast_exp2(m2 - M), w3 = fast_exp2(m3 - M);
    float inv = 1.0f / (w0 * l0 + w1 * l1 + w2 * l2 + w3 * l3);
    f32x4 a0 = *(const f32x4*)(po + ((size_t)row * 4 + 0) * 32 + d0);
    f32x4 a1 = *(const f32x4*)(po + ((size_t)row * 4 + 1) * 32 + d0);
    f32x4 a2 = *(const f32x4*)(po + ((size_t)row * 4 + 2) * 32 + d0);
    f32x4 a3 = *(const f32x4*)(po + ((size_t)row * 4 + 3) * 32 + d0);
    ushort4 st;
    st.x = f2bf((w0 * a0[0] + w1 * a1[0] + w2 * a2[0] + w3 * a3[0]) * inv);
    st.y = f2bf((w0 * a0[1] + w1 * a1[1] + w2 * a2[1] + w3 * a3[1]) * inv);
    st.z = f2bf((w0 * a0[2] + w1 * a1[2] + w2 * a2[2] + w3 * a3[2]) * inv);
    st.w = f2bf((w0 * a0[3] + w1 * a1[3] + w2 * a2[3] + w3 * a3[3]) * inv);
    int i = row & 4095;
    int bh = row >> 12;
    int b = bh >> 2, h = bh & 3;
    *(ushort4*)(attnt + ((size_t)(b * 4096 + i)) * 128 + h * 32 + d0) = st;
}

// ---------------- proj GEMM + bias + residual. grid 256 = b(2) x mt(4) x nt(32).
// Tile 64c x 128n, wave 32x64.
__global__ __launch_bounds__(256) void k_proj(const u16* __restrict__ wp, const u16* __restrict__ attnt,
                                              const float* __restrict__ pb, const float* __restrict__ x,
                                              float* __restrict__ out) {
    int bid = blockIdx.x;
    int b = bid >> 7;
    int r2 = bid & 127;
    int mt = r2 >> 5, nt = r2 & 31;
    int tid = threadIdx.x;
    int w = tid >> 6, lane = tid & 63, lr = lane & 15, lg = lane >> 4;
    int wr = w >> 1, wc = w & 1;
    int cb = mt * 64 + wr * 32;
    int nb = nt * 128 + wc * 64;
    f32x4 acc[2][4];
#pragma unroll
    for (int mi = 0; mi < 2; mi++)
#pragma unroll
        for (int ni = 0; ni < 4; ni++) acc[mi][ni] = (f32x4){0.f, 0.f, 0.f, 0.f};
    const u16* apan = wp + (cb + lr) * 128 + lg * 8;
    const u16* bpan = attnt + ((size_t)(b * 4096 + nb + lr)) * 128 + lg * 8;
#pragma unroll
    for (int kk = 0; kk < 128; kk += 32) {
        bf16x8 af[2], bfv[4];
#pragma unroll
        for (int mi = 0; mi < 2; mi++) af[mi] = *(const bf16x8*)(apan + mi * 16 * 128 + kk);
#pragma unroll
        for (int ni = 0; ni < 4; ni++) bfv[ni] = *(const bf16x8*)(bpan + ni * 16 * 128 + kk);
#pragma unroll
        for (int mi = 0; mi < 2; mi++)
#pragma unroll
            for (int ni = 0; ni < 4; ni++) acc[mi][ni] = MFMA16(af[mi], bfv[ni], acc[mi][ni]);
    }
#pragma unroll
    for (int mi = 0; mi < 2; mi++)
#pragma unroll
        for (int ni = 0; ni < 4; ni++) {
            int n = nb + ni * 16 + lr;
#pragma unroll
            for (int r = 0; r < 4; r++) {
                int c = cb + mi * 16 + lg * 4 + r;
                size_t idx = ((size_t)(b * 256 + c)) * 4096 + n;
                out[idx] = acc[mi][ni][r] + pb[c] + x[idx];
            }
        }
}

extern "C" void kernel_launch(void* const* d_in, const int* in_sizes, int n_in,
                              void* d_out, int out_size, void* d_ws, size_t ws_size,
                              hipStream_t stream) {
    const float* x = (const float*)d_in[0];
    const float* nw = (const float*)d_in[1];
    const float* nbv = (const float*)d_in[2];
    const float* qw = (const float*)d_in[3];
    const float* pw = (const float*)d_in[4];
    const float* pb = (const float*)d_in[5];
    float* out = (float*)d_out;
    char* ws = (char*)d_ws;

    float* psum = (float*)(ws + 0);
    float* psumsq = (float*)(ws + 1024);
    float* meanb = (float*)(ws + 2048);
    float* rstdb = (float*)(ws + 2112);
    u16* qwb = (u16*)(ws + 4096);            // ends 200704
    u16* pwb = (u16*)(ws + 200704);          // ends 266240
    u16* xnt = (u16*)(ws + 266240);          // ends 4460544
    u16* qkvt = (u16*)(ws + 4460544);        // ends 8654848
    u16* vnat = (u16*)(ws + 8654848);        // ends 10752000
    u16* attnt = (u16*)(ws + 10752000);      // ends 12849152
    float* po = (float*)(ws + 12849152);     // 16 MB, ends 29626368
    float* pml = (float*)(ws + 29626368);    // 1 MB, ends 30674944

    k_wconv<<<64, 256, 0, stream>>>(qw, pw, qwb, pwb);
    k_stats1<<<256, 256, 0, stream>>>(x, psum, psumsq);
    k_stats2<<<1, 64, 0, stream>>>(psum, psumsq, meanb, rstdb);
    k_normt<<<2048, 256, 0, stream>>>(x, nw, nbv, meanb, rstdb, xnt);
    k_qkv<<<384, 256, 0, stream>>>(qwb, xnt, qkvt, vnat);
    k_attn<<<512, 256, 0, stream>>>(qkvt, vnat, po, pml);
    k_comb<<<1024, 256, 0, stream>>>(po, pml, attnt);
    k_proj<<<256, 256, 0, stream>>>(pwb, attnt, pb, x, out);
}